// Round 1
// baseline (6203.768 us; speedup 1.0000x reference)
//
#include <hip/hip_runtime.h>
#include <hip/hip_bf16.h>
#include <cstdio>

#define N_NODES 100000
#define N_EDGES 1600000
#define D_NODE 128
#define D_EDGE 64
#define HID 128
#define HEADS 4
#define N_LAYERS 3
#define LN_EPS 1e-5f
#define NEG_SLOPE 0.2f
#define EE (N_EDGES + N_NODES)   // edges incl. self-loops

typedef unsigned short bfraw;

__device__ __forceinline__ float b2f(bfraw u) {
    return __uint_as_float(((unsigned)u) << 16);
}
__device__ __forceinline__ bfraw f2b(float f) {
    // round-to-nearest-even bf16 (inputs are well-behaved, no NaN handling needed)
    unsigned u = __float_as_uint(f);
    unsigned r = (u + 0x7fffu + ((u >> 16) & 1u)) >> 16;
    return (bfraw)r;
}
__device__ __forceinline__ unsigned encf(float f) {
    unsigned b = __float_as_uint(f);
    return (b & 0x80000000u) ? ~b : (b | 0x80000000u);
}
__device__ __forceinline__ float decf(unsigned e) {
    return __uint_as_float((e & 0x80000000u) ? (e & 0x7fffffffu) : ~e);
}
__device__ __forceinline__ float lrelu(float v) {
    return v > 0.f ? v : NEG_SLOPE * v;
}

// ---------------------------------------------------------------------------
// prep: wem[l][d] = mean_j We[l][d][j]; bem[l] = mean(be[l]); ewsum = 0
// ---------------------------------------------------------------------------
__global__ __launch_bounds__(256) void prep_kernel(
    const float* __restrict__ We, const float* __restrict__ be,
    float* __restrict__ wem, float* __restrict__ bem, float* __restrict__ ewsum) {
    int tid = threadIdx.x;
    if (tid < N_LAYERS * D_EDGE) {
        int l = tid / D_EDGE, d = tid % D_EDGE;
        const float* row = We + ((size_t)l * D_EDGE + d) * HID;
        float s = 0.f;
        for (int j = 0; j < HID; j++) s += row[j];
        wem[tid] = s * (1.0f / HID);
    } else if (tid < N_LAYERS * D_EDGE + N_LAYERS) {
        int l = tid - N_LAYERS * D_EDGE;
        const float* row = be + (size_t)l * HID;
        float s = 0.f;
        for (int j = 0; j < HID; j++) s += row[j];
        bem[l] = s * (1.0f / HID);
    } else if (tid < N_LAYERS * D_EDGE + 2 * N_LAYERS) {
        ewsum[tid - (N_LAYERS * D_EDGE + N_LAYERS)] = 0.f;
    }
}

// ---------------------------------------------------------------------------
// ew[l][e] = dot(edge_attr[e], wem[l]) + bem[l]; ewsum[l] += (wave-reduced)
// ---------------------------------------------------------------------------
__global__ __launch_bounds__(256) void ew_kernel(
    const float* __restrict__ ea, const float* __restrict__ wem,
    const float* __restrict__ bem, float* __restrict__ ew, float* __restrict__ ewsum) {
    __shared__ float wsh[N_LAYERS * D_EDGE];
    __shared__ float bsh[N_LAYERS];
    int tid = threadIdx.x;
    if (tid < N_LAYERS * D_EDGE) wsh[tid] = wem[tid];
    if (tid < N_LAYERS) bsh[tid] = bem[tid];
    __syncthreads();
    long long e = (long long)blockIdx.x * 256 + tid;
    float d0 = 0.f, d1 = 0.f, d2 = 0.f;
    if (e < N_EDGES) {
        const float4* row = (const float4*)(ea + (size_t)e * D_EDGE);
#pragma unroll
        for (int i = 0; i < D_EDGE / 4; i++) {
            float4 v = row[i];
            int c = i * 4;
            d0 += v.x * wsh[c] + v.y * wsh[c + 1] + v.z * wsh[c + 2] + v.w * wsh[c + 3];
            d1 += v.x * wsh[64 + c] + v.y * wsh[64 + c + 1] + v.z * wsh[64 + c + 2] + v.w * wsh[64 + c + 3];
            d2 += v.x * wsh[128 + c] + v.y * wsh[128 + c + 1] + v.z * wsh[128 + c + 2] + v.w * wsh[128 + c + 3];
        }
        d0 += bsh[0]; d1 += bsh[1]; d2 += bsh[2];
        ew[e] = d0;
        ew[(size_t)N_EDGES + e] = d1;
        ew[2 * (size_t)N_EDGES + e] = d2;
    }
    // wave-level reduce, one atomic triple per wave
    float s0 = d0, s1 = d1, s2 = d2;
    for (int o = 32; o; o >>= 1) {
        s0 += __shfl_xor(s0, o);
        s1 += __shfl_xor(s1, o);
        s2 += __shfl_xor(s2, o);
    }
    if ((tid & 63) == 0) {
        atomicAdd(&ewsum[0], s0);
        atomicAdd(&ewsum[1], s1);
        atomicAdd(&ewsum[2], s2);
    }
}

// ---------------------------------------------------------------------------
// SGEMM C[M,N] = act(A[M,128] @ B[128,N] + bias), fp32 SIMT, 64x64 tile
// ---------------------------------------------------------------------------
template <bool RELU, bool OUT_BF16>
__global__ __launch_bounds__(256) void sgemm_kernel(
    const float* __restrict__ A, const float* __restrict__ B,
    const float* __restrict__ bias, void* __restrict__ C, int M, int N) {
    const int BM = 64, BN = 64, BK = 16;
    __shared__ float As[BK][BM];
    __shared__ float Bs[BK][BN];
    int tid = threadIdx.x;
    int tx = tid & 15, ty = tid >> 4;
    int m0 = blockIdx.y * BM, n0 = blockIdx.x * BN;
    float acc[4][4] = {};
    int arow = tid >> 2;
    int acol = (tid & 3) * 4;
    int brow = tid >> 4;
    int bcol = (tid & 15) * 4;
    for (int k0 = 0; k0 < 128; k0 += BK) {
        float4 av = make_float4(0.f, 0.f, 0.f, 0.f);
        if (m0 + arow < M)
            av = *(const float4*)(A + (size_t)(m0 + arow) * 128 + k0 + acol);
        As[acol + 0][arow] = av.x;
        As[acol + 1][arow] = av.y;
        As[acol + 2][arow] = av.z;
        As[acol + 3][arow] = av.w;
        float4 bv = *(const float4*)(B + (size_t)(k0 + brow) * N + n0 + bcol);
        Bs[brow][bcol + 0] = bv.x;
        Bs[brow][bcol + 1] = bv.y;
        Bs[brow][bcol + 2] = bv.z;
        Bs[brow][bcol + 3] = bv.w;
        __syncthreads();
#pragma unroll
        for (int kk = 0; kk < BK; kk++) {
            float a[4], b[4];
#pragma unroll
            for (int i = 0; i < 4; i++) a[i] = As[kk][ty * 4 + i];
#pragma unroll
            for (int j = 0; j < 4; j++) b[j] = Bs[kk][tx * 4 + j];
#pragma unroll
            for (int i = 0; i < 4; i++)
#pragma unroll
                for (int j = 0; j < 4; j++) acc[i][j] += a[i] * b[j];
        }
        __syncthreads();
    }
#pragma unroll
    for (int i = 0; i < 4; i++) {
        int row = m0 + ty * 4 + i;
        if (row >= M) continue;
#pragma unroll
        for (int j = 0; j < 4; j++) {
            int col = n0 + tx * 4 + j;
            float v = acc[i][j];
            if (bias) v += bias[col];
            if (RELU) v = v > 0.f ? v : 0.f;
            if (OUT_BF16)
                ((bfraw*)C)[(size_t)row * N + col] = f2b(v);
            else
                ((float*)C)[(size_t)row * N + col] = v;
        }
    }
}

// ---------------------------------------------------------------------------
// a_s[n,hd] = dot(h[n,hd,:], att_src[hd,:]); same for a_d
// ---------------------------------------------------------------------------
__global__ __launch_bounds__(256) void att_kernel(
    const bfraw* __restrict__ h, const float* __restrict__ att_s_l,
    const float* __restrict__ att_d_l, float* __restrict__ a_s, float* __restrict__ a_d) {
    __shared__ float ss[HEADS * HID], sd[HEADS * HID];
    int tid = threadIdx.x;
    for (int i = tid; i < HEADS * HID; i += 256) {
        ss[i] = att_s_l[i];
        sd[i] = att_d_l[i];
    }
    __syncthreads();
    long long gid = (long long)blockIdx.x * 256 + tid;
    if (gid >= (long long)N_NODES * HEADS) return;
    int n = (int)(gid >> 2), hd = (int)(gid & 3);
    const uint4* hv = (const uint4*)(h + (size_t)n * (HEADS * HID) + hd * HID);
    const float* ssp = ss + hd * HID;
    const float* sdp = sd + hd * HID;
    float s = 0.f, d = 0.f;
#pragma unroll
    for (int i = 0; i < 16; i++) {
        uint4 u = hv[i];
        unsigned w[4] = {u.x, u.y, u.z, u.w};
#pragma unroll
        for (int j = 0; j < 4; j++) {
            float lo = __uint_as_float(w[j] << 16);
            float hi = __uint_as_float(w[j] & 0xffff0000u);
            int c = i * 8 + j * 2;
            s += lo * ssp[c] + hi * ssp[c + 1];
            d += lo * sdp[c] + hi * sdp[c + 1];
        }
    }
    a_s[gid] = s;
    a_d[gid] = d;
}

// ---------------------------------------------------------------------------
// per-layer init: y = 0, menc = enc(-1e30), denom = 0
// ---------------------------------------------------------------------------
__global__ __launch_bounds__(256) void init_kernel(
    float* __restrict__ y, unsigned* __restrict__ menc, float* __restrict__ denom) {
    long long i = (long long)blockIdx.x * 256 + threadIdx.x;
    if (i < (long long)N_NODES * HID) y[i] = 0.f;
    if (i < (long long)N_NODES * HEADS) {
        menc[i] = encf(-1e30f);
        denom[i] = 0.f;
    }
}

// ---------------------------------------------------------------------------
// pass 1: segment max of leaky_relu(a_s[src]+a_d[dst]+ew) via encoded atomicMax
// ---------------------------------------------------------------------------
__global__ __launch_bounds__(256) void max_kernel(
    const int* __restrict__ ei, const float* __restrict__ ew_l,
    const float* __restrict__ ewsum, int l,
    const float* __restrict__ a_s, const float* __restrict__ a_d,
    unsigned* __restrict__ menc) {
    long long e = (long long)blockIdx.x * 256 + threadIdx.x;
    if (e >= EE) return;
    int s, d;
    float w;
    if (e < N_EDGES) {
        s = ei[e];
        d = ei[N_EDGES + e];
        w = ew_l[e];
    } else {
        s = d = (int)(e - N_EDGES);
        w = ewsum[l] * (1.0f / N_EDGES);
    }
    float4 as4 = *(const float4*)(a_s + (size_t)s * 4);
    float4 ad4 = *(const float4*)(a_d + (size_t)d * 4);
    unsigned* mp = menc + (size_t)d * 4;
    atomicMax(mp + 0, encf(lrelu(as4.x + ad4.x + w)));
    atomicMax(mp + 1, encf(lrelu(as4.y + ad4.y + w)));
    atomicMax(mp + 2, encf(lrelu(as4.z + ad4.z + w)));
    atomicMax(mp + 3, encf(lrelu(as4.w + ad4.w + w)));
}

// ---------------------------------------------------------------------------
// pass 2: ex = exp(logit - m[dst]); denom[dst] += ex
// ---------------------------------------------------------------------------
__global__ __launch_bounds__(256) void exp_kernel(
    const int* __restrict__ ei, const float* __restrict__ ew_l,
    const float* __restrict__ ewsum, int l,
    const float* __restrict__ a_s, const float* __restrict__ a_d,
    const unsigned* __restrict__ menc, float* __restrict__ ex,
    float* __restrict__ denom) {
    long long e = (long long)blockIdx.x * 256 + threadIdx.x;
    if (e >= EE) return;
    int s, d;
    float w;
    if (e < N_EDGES) {
        s = ei[e];
        d = ei[N_EDGES + e];
        w = ew_l[e];
    } else {
        s = d = (int)(e - N_EDGES);
        w = ewsum[l] * (1.0f / N_EDGES);
    }
    float4 as4 = *(const float4*)(a_s + (size_t)s * 4);
    float4 ad4 = *(const float4*)(a_d + (size_t)d * 4);
    uint4 m4 = *(const uint4*)(menc + (size_t)d * 4);
    float e0 = __expf(lrelu(as4.x + ad4.x + w) - decf(m4.x));
    float e1 = __expf(lrelu(as4.y + ad4.y + w) - decf(m4.y));
    float e2 = __expf(lrelu(as4.z + ad4.z + w) - decf(m4.z));
    float e3 = __expf(lrelu(as4.w + ad4.w + w) - decf(m4.w));
    *(float4*)(ex + (size_t)e * 4) = make_float4(e0, e1, e2, e3);
    float* dp = denom + (size_t)d * 4;
    atomicAdd(dp + 0, e0);
    atomicAdd(dp + 1, e1);
    atomicAdd(dp + 2, e2);
    atomicAdd(dp + 3, e3);
}

// ---------------------------------------------------------------------------
// pass 3: y[dst,c] += 0.25 * sum_h alpha[e,h] * h[src,h,c]
// one thread per (edge, channel)
// ---------------------------------------------------------------------------
__global__ __launch_bounds__(256) void agg_kernel(
    const int* __restrict__ ei, const float* __restrict__ ex,
    const float* __restrict__ denom, const bfraw* __restrict__ h,
    float* __restrict__ y) {
    long long gid = (long long)blockIdx.x * 256 + threadIdx.x;
    if (gid >= (long long)EE * HID) return;
    int t = (int)(gid & 127);
    long long e = gid >> 7;
    int s, d;
    if (e < N_EDGES) {
        s = ei[e];
        d = ei[N_EDGES + e];
    } else {
        s = d = (int)(e - N_EDGES);
    }
    float4 exv = *(const float4*)(ex + (size_t)e * 4);
    float4 dn = *(const float4*)(denom + (size_t)d * 4);
    float a0 = exv.x / dn.x;
    float a1 = exv.y / dn.y;
    float a2 = exv.z / dn.z;
    float a3 = exv.w / dn.w;
    const bfraw* hr = h + (size_t)s * (HEADS * HID);
    float v = a0 * b2f(hr[t]) + a1 * b2f(hr[128 + t]) + a2 * b2f(hr[256 + t]) + a3 * b2f(hr[384 + t]);
    atomicAdd(y + (size_t)d * HID + t, 0.25f * v);
}

// ---------------------------------------------------------------------------
// LN + residual + relu: x = relu(x + LN(y + bg) * gamma + beta); one wave/node
// ---------------------------------------------------------------------------
__global__ __launch_bounds__(256) void ln_kernel(
    const float* __restrict__ y, const float* __restrict__ bg,
    const float* __restrict__ gamma, const float* __restrict__ beta,
    float* __restrict__ x) {
    int node = blockIdx.x * 4 + (threadIdx.x >> 6);
    int lane = threadIdx.x & 63;
    if (node >= N_NODES) return;
    const float* yr = y + (size_t)node * HID;
    float v0 = yr[lane] + bg[lane];
    float v1 = yr[64 + lane] + bg[64 + lane];
    float sum = v0 + v1;
    for (int o = 32; o; o >>= 1) sum += __shfl_xor(sum, o);
    float mu = sum * (1.f / HID);
    float c0 = v0 - mu, c1 = v1 - mu;
    float vs = c0 * c0 + c1 * c1;
    for (int o = 32; o; o >>= 1) vs += __shfl_xor(vs, o);
    float r = rsqrtf(vs * (1.f / HID) + LN_EPS);
    float o0 = c0 * r * gamma[lane] + beta[lane];
    float o1 = c1 * r * gamma[64 + lane] + beta[64 + lane];
    float* xr = x + (size_t)node * HID;
    float x0 = xr[lane] + o0;
    xr[lane] = x0 > 0.f ? x0 : 0.f;
    float x1 = xr[64 + lane] + o1;
    xr[64 + lane] = x1 > 0.f ? x1 : 0.f;
}

extern "C" void kernel_launch(void* const* d_in, const int* in_sizes, int n_in,
                              void* d_out, int out_size, void* d_ws, size_t ws_size,
                              hipStream_t stream) {
    const float* nf      = (const float*)d_in[0];
    const int*   ei      = (const int*)d_in[1];
    const float* ea      = (const float*)d_in[2];
    const float* W0      = (const float*)d_in[3];
    const float* b0      = (const float*)d_in[4];
    const float* We      = (const float*)d_in[5];
    const float* be      = (const float*)d_in[6];
    const float* Wg      = (const float*)d_in[7];
    const float* att_src = (const float*)d_in[8];
    const float* att_dst = (const float*)d_in[9];
    const float* bg      = (const float*)d_in[10];
    const float* gamma   = (const float*)d_in[11];
    const float* beta    = (const float*)d_in[12];
    float* x = (float*)d_out;  // x lives in d_out throughout

    char* p = (char*)d_ws;
    auto alloc = [&](size_t bytes) -> void* {
        void* r = (void*)p;
        p += (bytes + 255) & ~(size_t)255;
        return r;
    };
    bfraw*    h     = (bfraw*)alloc((size_t)N_NODES * HEADS * HID * sizeof(bfraw));
    float*    y     = (float*)alloc((size_t)N_NODES * HID * sizeof(float));
    float*    a_s   = (float*)alloc((size_t)N_NODES * HEADS * sizeof(float));
    float*    a_d   = (float*)alloc((size_t)N_NODES * HEADS * sizeof(float));
    float*    ew    = (float*)alloc((size_t)N_LAYERS * N_EDGES * sizeof(float));
    float*    ex    = (float*)alloc((size_t)EE * HEADS * sizeof(float));
    unsigned* menc  = (unsigned*)alloc((size_t)N_NODES * HEADS * sizeof(unsigned));
    float*    denom = (float*)alloc((size_t)N_NODES * HEADS * sizeof(float));
    float*    wem   = (float*)alloc((size_t)N_LAYERS * D_EDGE * sizeof(float));
    float*    bem   = (float*)alloc((size_t)N_LAYERS * sizeof(float));
    float*    ewsum = (float*)alloc((size_t)N_LAYERS * sizeof(float));
    size_t need = (size_t)(p - (char*)d_ws);
    if (need > ws_size) {
        fprintf(stderr, "kernel_launch: workspace too small: need %zu have %zu\n", need, ws_size);
        return;
    }

    prep_kernel<<<1, 256, 0, stream>>>(We, be, wem, bem, ewsum);
    ew_kernel<<<(N_EDGES + 255) / 256, 256, 0, stream>>>(ea, wem, bem, ew, ewsum);
    // node encoder: x = relu(nf @ W0 + b0)
    sgemm_kernel<true, false><<<dim3(HID / 64, (N_NODES + 63) / 64), 256, 0, stream>>>(
        nf, W0, b0, (void*)x, N_NODES, HID);

    for (int l = 0; l < N_LAYERS; l++) {
        // h = x @ Wg[l]  (bf16 storage)
        sgemm_kernel<false, true><<<dim3(HEADS * HID / 64, (N_NODES + 63) / 64), 256, 0, stream>>>(
            x, Wg + (size_t)l * HID * HEADS * HID, nullptr, (void*)h, N_NODES, HEADS * HID);
        att_kernel<<<((long long)N_NODES * HEADS + 255) / 256, 256, 0, stream>>>(
            h, att_src + (size_t)l * HEADS * HID, att_dst + (size_t)l * HEADS * HID, a_s, a_d);
        init_kernel<<<((long long)N_NODES * HID + 255) / 256, 256, 0, stream>>>(y, menc, denom);
        max_kernel<<<(EE + 255) / 256, 256, 0, stream>>>(
            ei, ew + (size_t)l * N_EDGES, ewsum, l, a_s, a_d, menc);
        exp_kernel<<<(EE + 255) / 256, 256, 0, stream>>>(
            ei, ew + (size_t)l * N_EDGES, ewsum, l, a_s, a_d, menc, ex, denom);
        agg_kernel<<<(unsigned)(((long long)EE * HID + 255) / 256), 256, 0, stream>>>(
            ei, ex, denom, h, y);
        ln_kernel<<<(N_NODES + 3) / 4, 256, 0, stream>>>(
            y, bg + (size_t)l * HID, gamma + (size_t)l * HID, beta + (size_t)l * HID, x);
    }
}

// Round 2
// 5396.173 us; speedup vs baseline: 1.1497x; 1.1497x over previous
//
#include <hip/hip_runtime.h>
#include <hip/hip_bf16.h>
#include <cstdio>

#define N_NODES 100000
#define N_EDGES 1600000
#define D_NODE 128
#define D_EDGE 64
#define HID 128
#define HEADS 4
#define N_LAYERS 3
#define LN_EPS 1e-5f
#define NEG_SLOPE 0.2f
#define EE (N_EDGES + N_NODES)   // edges incl. self-loops
#define EW_GRID ((N_EDGES + 255) / 256)   // 6250 blocks

typedef unsigned short bfraw;

__device__ __forceinline__ float b2f(bfraw u) {
    return __uint_as_float(((unsigned)u) << 16);
}
__device__ __forceinline__ bfraw f2b(float f) {
    // round-to-nearest-even bf16 (inputs are well-behaved, no NaN handling needed)
    unsigned u = __float_as_uint(f);
    unsigned r = (u + 0x7fffu + ((u >> 16) & 1u)) >> 16;
    return (bfraw)r;
}
__device__ __forceinline__ unsigned encf(float f) {
    unsigned b = __float_as_uint(f);
    return (b & 0x80000000u) ? ~b : (b | 0x80000000u);
}
__device__ __forceinline__ float decf(unsigned e) {
    return __uint_as_float((e & 0x80000000u) ? (e & 0x7fffffffu) : ~e);
}
__device__ __forceinline__ float lrelu(float v) {
    return v > 0.f ? v : NEG_SLOPE * v;
}

// ---------------------------------------------------------------------------
// prep: wem[l][d] = mean_j We[l][d][j]; bem[l] = mean(be[l])
// ---------------------------------------------------------------------------
__global__ __launch_bounds__(256) void prep_kernel(
    const float* __restrict__ We, const float* __restrict__ be,
    float* __restrict__ wem, float* __restrict__ bem) {
    int tid = threadIdx.x;
    if (tid < N_LAYERS * D_EDGE) {
        int l = tid / D_EDGE, d = tid % D_EDGE;
        const float* row = We + ((size_t)l * D_EDGE + d) * HID;
        float s = 0.f;
        for (int j = 0; j < HID; j++) s += row[j];
        wem[tid] = s * (1.0f / HID);
    } else if (tid < N_LAYERS * D_EDGE + N_LAYERS) {
        int l = tid - N_LAYERS * D_EDGE;
        const float* row = be + (size_t)l * HID;
        float s = 0.f;
        for (int j = 0; j < HID; j++) s += row[j];
        bem[l] = s * (1.0f / HID);
    }
}

// ---------------------------------------------------------------------------
// ew[l][e] = dot(edge_attr[e], wem[l]) + bem[l]
// block-level partial sums -> partial[l][blk]  (NO contended global atomics:
// R0 post-mortem: 75k same-line atomicAdds serialized at the TCC, 971us)
// ---------------------------------------------------------------------------
__global__ __launch_bounds__(256) void ew_kernel(
    const float* __restrict__ ea, const float* __restrict__ wem,
    const float* __restrict__ bem, float* __restrict__ ew,
    float* __restrict__ partial) {
    __shared__ float wsh[N_LAYERS * D_EDGE];
    __shared__ float bsh[N_LAYERS];
    __shared__ float red[4][3];
    int tid = threadIdx.x;
    if (tid < N_LAYERS * D_EDGE) wsh[tid] = wem[tid];
    if (tid < N_LAYERS) bsh[tid] = bem[tid];
    __syncthreads();
    long long e = (long long)blockIdx.x * 256 + tid;
    float d0 = 0.f, d1 = 0.f, d2 = 0.f;
    if (e < N_EDGES) {
        const float4* row = (const float4*)(ea + (size_t)e * D_EDGE);
#pragma unroll
        for (int i = 0; i < D_EDGE / 4; i++) {
            float4 v = row[i];
            int c = i * 4;
            d0 += v.x * wsh[c] + v.y * wsh[c + 1] + v.z * wsh[c + 2] + v.w * wsh[c + 3];
            d1 += v.x * wsh[64 + c] + v.y * wsh[64 + c + 1] + v.z * wsh[64 + c + 2] + v.w * wsh[64 + c + 3];
            d2 += v.x * wsh[128 + c] + v.y * wsh[128 + c + 1] + v.z * wsh[128 + c + 2] + v.w * wsh[128 + c + 3];
        }
        ew[e] = d0 + bsh[0];
        ew[(size_t)N_EDGES + e] = d1 + bsh[1];
        ew[2 * (size_t)N_EDGES + e] = d2 + bsh[2];
    }
    // wave reduce (sum of raw dots, bias added analytically in reduce kernel)
    float s0 = d0, s1 = d1, s2 = d2;
    for (int o = 32; o; o >>= 1) {
        s0 += __shfl_xor(s0, o);
        s1 += __shfl_xor(s1, o);
        s2 += __shfl_xor(s2, o);
    }
    int wid = tid >> 6;
    if ((tid & 63) == 0) {
        red[wid][0] = s0;
        red[wid][1] = s1;
        red[wid][2] = s2;
    }
    __syncthreads();
    if (tid < 3) {
        partial[(size_t)tid * EW_GRID + blockIdx.x] =
            red[0][tid] + red[1][tid] + red[2][tid] + red[3][tid];
    }
}

// ---------------------------------------------------------------------------
// reduce per-block partials -> ewsum[l] = sum_e ew[l][e]
// ---------------------------------------------------------------------------
__global__ __launch_bounds__(256) void ewred_kernel(
    const float* __restrict__ partial, const float* __restrict__ bem,
    float* __restrict__ ewsum) {
    __shared__ float red[4];
    int l = blockIdx.x;
    int tid = threadIdx.x;
    float s = 0.f;
    for (int i = tid; i < EW_GRID; i += 256) s += partial[(size_t)l * EW_GRID + i];
    for (int o = 32; o; o >>= 1) s += __shfl_xor(s, o);
    int wid = tid >> 6;
    if ((tid & 63) == 0) red[wid] = s;
    __syncthreads();
    if (tid == 0)
        ewsum[l] = red[0] + red[1] + red[2] + red[3] + bem[l] * (float)N_EDGES;
}

// ---------------------------------------------------------------------------
// SGEMM C[M,N] = act(A[M,128] @ B[128,N] + bias), fp32 SIMT, 64x64 tile
// ---------------------------------------------------------------------------
template <bool RELU, bool OUT_BF16>
__global__ __launch_bounds__(256) void sgemm_kernel(
    const float* __restrict__ A, const float* __restrict__ B,
    const float* __restrict__ bias, void* __restrict__ C, int M, int N) {
    const int BM = 64, BN = 64, BK = 16;
    __shared__ float As[BK][BM];
    __shared__ float Bs[BK][BN];
    int tid = threadIdx.x;
    int tx = tid & 15, ty = tid >> 4;
    int m0 = blockIdx.y * BM, n0 = blockIdx.x * BN;
    float acc[4][4] = {};
    int arow = tid >> 2;
    int acol = (tid & 3) * 4;
    int brow = tid >> 4;
    int bcol = (tid & 15) * 4;
    for (int k0 = 0; k0 < 128; k0 += BK) {
        float4 av = make_float4(0.f, 0.f, 0.f, 0.f);
        if (m0 + arow < M)
            av = *(const float4*)(A + (size_t)(m0 + arow) * 128 + k0 + acol);
        As[acol + 0][arow] = av.x;
        As[acol + 1][arow] = av.y;
        As[acol + 2][arow] = av.z;
        As[acol + 3][arow] = av.w;
        float4 bv = *(const float4*)(B + (size_t)(k0 + brow) * N + n0 + bcol);
        Bs[brow][bcol + 0] = bv.x;
        Bs[brow][bcol + 1] = bv.y;
        Bs[brow][bcol + 2] = bv.z;
        Bs[brow][bcol + 3] = bv.w;
        __syncthreads();
#pragma unroll
        for (int kk = 0; kk < BK; kk++) {
            float a[4], b[4];
#pragma unroll
            for (int i = 0; i < 4; i++) a[i] = As[kk][ty * 4 + i];
#pragma unroll
            for (int j = 0; j < 4; j++) b[j] = Bs[kk][tx * 4 + j];
#pragma unroll
            for (int i = 0; i < 4; i++)
#pragma unroll
                for (int j = 0; j < 4; j++) acc[i][j] += a[i] * b[j];
        }
        __syncthreads();
    }
#pragma unroll
    for (int i = 0; i < 4; i++) {
        int row = m0 + ty * 4 + i;
        if (row >= M) continue;
#pragma unroll
        for (int j = 0; j < 4; j++) {
            int col = n0 + tx * 4 + j;
            float v = acc[i][j];
            if (bias) v += bias[col];
            if (RELU) v = v > 0.f ? v : 0.f;
            if (OUT_BF16)
                ((bfraw*)C)[(size_t)row * N + col] = f2b(v);
            else
                ((float*)C)[(size_t)row * N + col] = v;
        }
    }
}

// ---------------------------------------------------------------------------
// a_s[n,hd] = dot(h[n,hd,:], att_src[hd,:]); same for a_d
// ---------------------------------------------------------------------------
__global__ __launch_bounds__(256) void att_kernel(
    const bfraw* __restrict__ h, const float* __restrict__ att_s_l,
    const float* __restrict__ att_d_l, float* __restrict__ a_s, float* __restrict__ a_d) {
    __shared__ float ss[HEADS * HID], sd[HEADS * HID];
    int tid = threadIdx.x;
    for (int i = tid; i < HEADS * HID; i += 256) {
        ss[i] = att_s_l[i];
        sd[i] = att_d_l[i];
    }
    __syncthreads();
    long long gid = (long long)blockIdx.x * 256 + tid;
    if (gid >= (long long)N_NODES * HEADS) return;
    int n = (int)(gid >> 2), hd = (int)(gid & 3);
    const uint4* hv = (const uint4*)(h + (size_t)n * (HEADS * HID) + hd * HID);
    const float* ssp = ss + hd * HID;
    const float* sdp = sd + hd * HID;
    float s = 0.f, d = 0.f;
#pragma unroll
    for (int i = 0; i < 16; i++) {
        uint4 u = hv[i];
        unsigned w[4] = {u.x, u.y, u.z, u.w};
#pragma unroll
        for (int j = 0; j < 4; j++) {
            float lo = __uint_as_float(w[j] << 16);
            float hi = __uint_as_float(w[j] & 0xffff0000u);
            int c = i * 8 + j * 2;
            s += lo * ssp[c] + hi * ssp[c + 1];
            d += lo * sdp[c] + hi * sdp[c + 1];
        }
    }
    a_s[gid] = s;
    a_d[gid] = d;
}

// ---------------------------------------------------------------------------
// per-layer init: y = 0, menc = enc(-1e30), denom = 0
// ---------------------------------------------------------------------------
__global__ __launch_bounds__(256) void init_kernel(
    float* __restrict__ y, unsigned* __restrict__ menc, float* __restrict__ denom) {
    long long i = (long long)blockIdx.x * 256 + threadIdx.x;
    if (i < (long long)N_NODES * HID) y[i] = 0.f;
    if (i < (long long)N_NODES * HEADS) {
        menc[i] = encf(-1e30f);
        denom[i] = 0.f;
    }
}

// ---------------------------------------------------------------------------
// pass 1: segment max of leaky_relu(a_s[src]+a_d[dst]+ew) via encoded atomicMax
// ---------------------------------------------------------------------------
__global__ __launch_bounds__(256) void max_kernel(
    const int* __restrict__ ei, const float* __restrict__ ew_l,
    const float* __restrict__ ewsum, int l,
    const float* __restrict__ a_s, const float* __restrict__ a_d,
    unsigned* __restrict__ menc) {
    long long e = (long long)blockIdx.x * 256 + threadIdx.x;
    if (e >= EE) return;
    int s, d;
    float w;
    if (e < N_EDGES) {
        s = ei[e];
        d = ei[N_EDGES + e];
        w = ew_l[e];
    } else {
        s = d = (int)(e - N_EDGES);
        w = ewsum[l] * (1.0f / N_EDGES);
    }
    float4 as4 = *(const float4*)(a_s + (size_t)s * 4);
    float4 ad4 = *(const float4*)(a_d + (size_t)d * 4);
    unsigned* mp = menc + (size_t)d * 4;
    atomicMax(mp + 0, encf(lrelu(as4.x + ad4.x + w)));
    atomicMax(mp + 1, encf(lrelu(as4.y + ad4.y + w)));
    atomicMax(mp + 2, encf(lrelu(as4.z + ad4.z + w)));
    atomicMax(mp + 3, encf(lrelu(as4.w + ad4.w + w)));
}

// ---------------------------------------------------------------------------
// pass 2: ex = exp(logit - m[dst]); denom[dst] += ex
// ---------------------------------------------------------------------------
__global__ __launch_bounds__(256) void exp_kernel(
    const int* __restrict__ ei, const float* __restrict__ ew_l,
    const float* __restrict__ ewsum, int l,
    const float* __restrict__ a_s, const float* __restrict__ a_d,
    const unsigned* __restrict__ menc, float* __restrict__ ex,
    float* __restrict__ denom) {
    long long e = (long long)blockIdx.x * 256 + threadIdx.x;
    if (e >= EE) return;
    int s, d;
    float w;
    if (e < N_EDGES) {
        s = ei[e];
        d = ei[N_EDGES + e];
        w = ew_l[e];
    } else {
        s = d = (int)(e - N_EDGES);
        w = ewsum[l] * (1.0f / N_EDGES);
    }
    float4 as4 = *(const float4*)(a_s + (size_t)s * 4);
    float4 ad4 = *(const float4*)(a_d + (size_t)d * 4);
    uint4 m4 = *(const uint4*)(menc + (size_t)d * 4);
    float e0 = __expf(lrelu(as4.x + ad4.x + w) - decf(m4.x));
    float e1 = __expf(lrelu(as4.y + ad4.y + w) - decf(m4.y));
    float e2 = __expf(lrelu(as4.z + ad4.z + w) - decf(m4.z));
    float e3 = __expf(lrelu(as4.w + ad4.w + w) - decf(m4.w));
    *(float4*)(ex + (size_t)e * 4) = make_float4(e0, e1, e2, e3);
    float* dp = denom + (size_t)d * 4;
    atomicAdd(dp + 0, e0);
    atomicAdd(dp + 1, e1);
    atomicAdd(dp + 2, e2);
    atomicAdd(dp + 3, e3);
}

// ---------------------------------------------------------------------------
// pass 3: y[dst,c] += 0.25 * sum_h alpha[e,h] * h[src,h,c]
// one thread per (edge, channel)
// ---------------------------------------------------------------------------
__global__ __launch_bounds__(256) void agg_kernel(
    const int* __restrict__ ei, const float* __restrict__ ex,
    const float* __restrict__ denom, const bfraw* __restrict__ h,
    float* __restrict__ y) {
    long long gid = (long long)blockIdx.x * 256 + threadIdx.x;
    if (gid >= (long long)EE * HID) return;
    int t = (int)(gid & 127);
    long long e = gid >> 7;
    int s, d;
    if (e < N_EDGES) {
        s = ei[e];
        d = ei[N_EDGES + e];
    } else {
        s = d = (int)(e - N_EDGES);
    }
    float4 exv = *(const float4*)(ex + (size_t)e * 4);
    float4 dn = *(const float4*)(denom + (size_t)d * 4);
    float a0 = exv.x / dn.x;
    float a1 = exv.y / dn.y;
    float a2 = exv.z / dn.z;
    float a3 = exv.w / dn.w;
    const bfraw* hr = h + (size_t)s * (HEADS * HID);
    float v = a0 * b2f(hr[t]) + a1 * b2f(hr[128 + t]) + a2 * b2f(hr[256 + t]) + a3 * b2f(hr[384 + t]);
    atomicAdd(y + (size_t)d * HID + t, 0.25f * v);
}

// ---------------------------------------------------------------------------
// LN + residual + relu: x = relu(x + LN(y + bg) * gamma + beta); one wave/node
// ---------------------------------------------------------------------------
__global__ __launch_bounds__(256) void ln_kernel(
    const float* __restrict__ y, const float* __restrict__ bg,
    const float* __restrict__ gamma, const float* __restrict__ beta,
    float* __restrict__ x) {
    int node = blockIdx.x * 4 + (threadIdx.x >> 6);
    int lane = threadIdx.x & 63;
    if (node >= N_NODES) return;
    const float* yr = y + (size_t)node * HID;
    float v0 = yr[lane] + bg[lane];
    float v1 = yr[64 + lane] + bg[64 + lane];
    float sum = v0 + v1;
    for (int o = 32; o; o >>= 1) sum += __shfl_xor(sum, o);
    float mu = sum * (1.f / HID);
    float c0 = v0 - mu, c1 = v1 - mu;
    float vs = c0 * c0 + c1 * c1;
    for (int o = 32; o; o >>= 1) vs += __shfl_xor(vs, o);
    float r = rsqrtf(vs * (1.f / HID) + LN_EPS);
    float o0 = c0 * r * gamma[lane] + beta[lane];
    float o1 = c1 * r * gamma[64 + lane] + beta[64 + lane];
    float* xr = x + (size_t)node * HID;
    float x0 = xr[lane] + o0;
    xr[lane] = x0 > 0.f ? x0 : 0.f;
    float x1 = xr[64 + lane] + o1;
    xr[64 + lane] = x1 > 0.f ? x1 : 0.f;
}

extern "C" void kernel_launch(void* const* d_in, const int* in_sizes, int n_in,
                              void* d_out, int out_size, void* d_ws, size_t ws_size,
                              hipStream_t stream) {
    const float* nf      = (const float*)d_in[0];
    const int*   ei      = (const int*)d_in[1];
    const float* ea      = (const float*)d_in[2];
    const float* W0      = (const float*)d_in[3];
    const float* b0      = (const float*)d_in[4];
    const float* We      = (const float*)d_in[5];
    const float* be      = (const float*)d_in[6];
    const float* Wg      = (const float*)d_in[7];
    const float* att_src = (const float*)d_in[8];
    const float* att_dst = (const float*)d_in[9];
    const float* bg      = (const float*)d_in[10];
    const float* gamma   = (const float*)d_in[11];
    const float* beta    = (const float*)d_in[12];
    float* x = (float*)d_out;  // x lives in d_out throughout

    char* p = (char*)d_ws;
    auto alloc = [&](size_t bytes) -> void* {
        void* r = (void*)p;
        p += (bytes + 255) & ~(size_t)255;
        return r;
    };
    bfraw*    h       = (bfraw*)alloc((size_t)N_NODES * HEADS * HID * sizeof(bfraw));
    float*    y       = (float*)alloc((size_t)N_NODES * HID * sizeof(float));
    float*    a_s     = (float*)alloc((size_t)N_NODES * HEADS * sizeof(float));
    float*    a_d     = (float*)alloc((size_t)N_NODES * HEADS * sizeof(float));
    float*    ew      = (float*)alloc((size_t)N_LAYERS * N_EDGES * sizeof(float));
    float*    ex      = (float*)alloc((size_t)EE * HEADS * sizeof(float));
    unsigned* menc    = (unsigned*)alloc((size_t)N_NODES * HEADS * sizeof(unsigned));
    float*    denom   = (float*)alloc((size_t)N_NODES * HEADS * sizeof(float));
    float*    wem     = (float*)alloc((size_t)N_LAYERS * D_EDGE * sizeof(float));
    float*    bem     = (float*)alloc((size_t)N_LAYERS * sizeof(float));
    float*    ewsum   = (float*)alloc((size_t)N_LAYERS * sizeof(float));
    float*    partial = (float*)alloc((size_t)N_LAYERS * EW_GRID * sizeof(float));
    size_t need = (size_t)(p - (char*)d_ws);
    if (need > ws_size) {
        fprintf(stderr, "kernel_launch: workspace too small: need %zu have %zu\n", need, ws_size);
        return;
    }

    prep_kernel<<<1, 256, 0, stream>>>(We, be, wem, bem);
    ew_kernel<<<EW_GRID, 256, 0, stream>>>(ea, wem, bem, ew, partial);
    ewred_kernel<<<N_LAYERS, 256, 0, stream>>>(partial, bem, ewsum);
    // node encoder: x = relu(nf @ W0 + b0)
    sgemm_kernel<true, false><<<dim3(HID / 64, (N_NODES + 63) / 64), 256, 0, stream>>>(
        nf, W0, b0, (void*)x, N_NODES, HID);

    for (int l = 0; l < N_LAYERS; l++) {
        // h = x @ Wg[l]  (bf16 storage)
        sgemm_kernel<false, true><<<dim3(HEADS * HID / 64, (N_NODES + 63) / 64), 256, 0, stream>>>(
            x, Wg + (size_t)l * HID * HEADS * HID, nullptr, (void*)h, N_NODES, HEADS * HID);
        att_kernel<<<((long long)N_NODES * HEADS + 255) / 256, 256, 0, stream>>>(
            h, att_src + (size_t)l * HEADS * HID, att_dst + (size_t)l * HEADS * HID, a_s, a_d);
        init_kernel<<<((long long)N_NODES * HID + 255) / 256, 256, 0, stream>>>(y, menc, denom);
        max_kernel<<<(EE + 255) / 256, 256, 0, stream>>>(
            ei, ew + (size_t)l * N_EDGES, ewsum, l, a_s, a_d, menc);
        exp_kernel<<<(EE + 255) / 256, 256, 0, stream>>>(
            ei, ew + (size_t)l * N_EDGES, ewsum, l, a_s, a_d, menc, ex, denom);
        agg_kernel<<<(unsigned)(((long long)EE * HID + 255) / 256), 256, 0, stream>>>(
            ei, ex, denom, h, y);
        ln_kernel<<<(N_NODES + 3) / 4, 256, 0, stream>>>(
            y, bg + (size_t)l * HID, gamma + (size_t)l * HID, beta + (size_t)l * HID, x);
    }
}

// Round 3
// 2659.311 us; speedup vs baseline: 2.3328x; 2.0292x over previous
//
#include <hip/hip_runtime.h>
#include <hip/hip_bf16.h>
#include <cstdio>

#define N_NODES 100000
#define N_EDGES 1600000
#define D_NODE 128
#define D_EDGE 64
#define HID 128
#define HEADS 4
#define N_LAYERS 3
#define LN_EPS 1e-5f
#define NEG_SLOPE 0.2f
#define EE (N_EDGES + N_NODES)            // edges incl. self-loops
#define EW_GRID ((N_EDGES + 255) / 256)   // 6250 blocks
#define SCAN_THREADS 1024
#define SCAN_CHUNK ((N_NODES + SCAN_THREADS - 1) / SCAN_THREADS)  // 98

typedef unsigned short bfraw;

__device__ __forceinline__ float b2f(bfraw u) {
    return __uint_as_float(((unsigned)u) << 16);
}
__device__ __forceinline__ bfraw f2b(float f) {
    unsigned u = __float_as_uint(f);
    unsigned r = (u + 0x7fffu + ((u >> 16) & 1u)) >> 16;
    return (bfraw)r;
}
__device__ __forceinline__ float lrelu(float v) {
    return v > 0.f ? v : NEG_SLOPE * v;
}

// ---------------------------------------------------------------------------
// prep: wem[l][d] = mean_j We[l][d][j]; bem[l] = mean(be[l])
// ---------------------------------------------------------------------------
__global__ __launch_bounds__(256) void prep_kernel(
    const float* __restrict__ We, const float* __restrict__ be,
    float* __restrict__ wem, float* __restrict__ bem) {
    int tid = threadIdx.x;
    if (tid < N_LAYERS * D_EDGE) {
        int l = tid / D_EDGE, d = tid % D_EDGE;
        const float* row = We + ((size_t)l * D_EDGE + d) * HID;
        float s = 0.f;
        for (int j = 0; j < HID; j++) s += row[j];
        wem[tid] = s * (1.0f / HID);
    } else if (tid < N_LAYERS * D_EDGE + N_LAYERS) {
        int l = tid - N_LAYERS * D_EDGE;
        const float* row = be + (size_t)l * HID;
        float s = 0.f;
        for (int j = 0; j < HID; j++) s += row[j];
        bem[l] = s * (1.0f / HID);
    }
}

// ---------------------------------------------------------------------------
// ew[l][e] = dot(edge_attr[e], wem[l]) + bem[l]; block partials (no atomics)
// ---------------------------------------------------------------------------
__global__ __launch_bounds__(256) void ew_kernel(
    const float* __restrict__ ea, const float* __restrict__ wem,
    const float* __restrict__ bem, float* __restrict__ ew,
    float* __restrict__ partial) {
    __shared__ float wsh[N_LAYERS * D_EDGE];
    __shared__ float bsh[N_LAYERS];
    __shared__ float red[4][3];
    int tid = threadIdx.x;
    if (tid < N_LAYERS * D_EDGE) wsh[tid] = wem[tid];
    if (tid < N_LAYERS) bsh[tid] = bem[tid];
    __syncthreads();
    long long e = (long long)blockIdx.x * 256 + tid;
    float d0 = 0.f, d1 = 0.f, d2 = 0.f;
    if (e < N_EDGES) {
        const float4* row = (const float4*)(ea + (size_t)e * D_EDGE);
#pragma unroll
        for (int i = 0; i < D_EDGE / 4; i++) {
            float4 v = row[i];
            int c = i * 4;
            d0 += v.x * wsh[c] + v.y * wsh[c + 1] + v.z * wsh[c + 2] + v.w * wsh[c + 3];
            d1 += v.x * wsh[64 + c] + v.y * wsh[64 + c + 1] + v.z * wsh[64 + c + 2] + v.w * wsh[64 + c + 3];
            d2 += v.x * wsh[128 + c] + v.y * wsh[128 + c + 1] + v.z * wsh[128 + c + 2] + v.w * wsh[128 + c + 3];
        }
        ew[e] = d0 + bsh[0];
        ew[(size_t)N_EDGES + e] = d1 + bsh[1];
        ew[2 * (size_t)N_EDGES + e] = d2 + bsh[2];
    }
    float s0 = d0, s1 = d1, s2 = d2;
    for (int o = 32; o; o >>= 1) {
        s0 += __shfl_xor(s0, o);
        s1 += __shfl_xor(s1, o);
        s2 += __shfl_xor(s2, o);
    }
    int wid = tid >> 6;
    if ((tid & 63) == 0) {
        red[wid][0] = s0;
        red[wid][1] = s1;
        red[wid][2] = s2;
    }
    __syncthreads();
    if (tid < 3) {
        partial[(size_t)tid * EW_GRID + blockIdx.x] =
            red[0][tid] + red[1][tid] + red[2][tid] + red[3][tid];
    }
}

__global__ __launch_bounds__(256) void ewred_kernel(
    const float* __restrict__ partial, const float* __restrict__ bem,
    float* __restrict__ ewsum) {
    __shared__ float red[4];
    int l = blockIdx.x;
    int tid = threadIdx.x;
    float s = 0.f;
    for (int i = tid; i < EW_GRID; i += 256) s += partial[(size_t)l * EW_GRID + i];
    for (int o = 32; o; o >>= 1) s += __shfl_xor(s, o);
    int wid = tid >> 6;
    if ((tid & 63) == 0) red[wid] = s;
    __syncthreads();
    if (tid == 0)
        ewsum[l] = red[0] + red[1] + red[2] + red[3] + bem[l] * (float)N_EDGES;
}

// ---------------------------------------------------------------------------
// CSR build: deg=1 (self-loop) -> histogram -> single-block scan -> scatter
// self-loop reserved at slot rowptr[d]; real edges fill rowptr[d]+1 ...
// ---------------------------------------------------------------------------
__global__ __launch_bounds__(256) void deginit_kernel(int* __restrict__ deg) {
    int i = blockIdx.x * 256 + threadIdx.x;
    if (i < N_NODES) deg[i] = 1;
}

__global__ __launch_bounds__(256) void hist_kernel(
    const int* __restrict__ ei, int* __restrict__ deg) {
    int e = blockIdx.x * 256 + threadIdx.x;
    if (e < N_EDGES) atomicAdd(&deg[ei[N_EDGES + e]], 1);
}

__global__ __launch_bounds__(SCAN_THREADS) void scan_kernel(
    const int* __restrict__ deg, int* __restrict__ rowptr, int* __restrict__ woff) {
    __shared__ int part[SCAN_THREADS];
    int tid = threadIdx.x;
    int lo = tid * SCAN_CHUNK;
    int hi = lo + SCAN_CHUNK < N_NODES ? lo + SCAN_CHUNK : N_NODES;
    int s = 0;
    for (int i = lo; i < hi; i++) s += deg[i];
    part[tid] = s;
    __syncthreads();
    for (int off = 1; off < SCAN_THREADS; off <<= 1) {
        int t = (tid >= off) ? part[tid - off] : 0;
        __syncthreads();
        part[tid] += t;
        __syncthreads();
    }
    int run = (tid == 0) ? 0 : part[tid - 1];
    for (int i = lo; i < hi; i++) {
        rowptr[i] = run;
        woff[i] = run + 1;  // slot 0 of each segment reserved for self-loop
        run += deg[i];
    }
    if (tid == 0) rowptr[N_NODES] = EE;
}

__global__ __launch_bounds__(256) void scatter_kernel(
    const int* __restrict__ ei, const float* __restrict__ ew,
    int* __restrict__ woff, int* __restrict__ csr_src,
    float* __restrict__ csr_ew) {
    int e = blockIdx.x * 256 + threadIdx.x;
    if (e >= N_EDGES) return;
    int d = ei[N_EDGES + e];
    int pos = atomicAdd(&woff[d], 1);
    csr_src[pos] = ei[e];
    csr_ew[pos] = ew[e];
    csr_ew[(size_t)EE + pos] = ew[(size_t)N_EDGES + e];
    csr_ew[2 * (size_t)EE + pos] = ew[2 * (size_t)N_EDGES + e];
}

__global__ __launch_bounds__(256) void selfloop_kernel(
    const int* __restrict__ rowptr, const float* __restrict__ ewsum,
    int* __restrict__ csr_src, float* __restrict__ csr_ew) {
    int d = blockIdx.x * 256 + threadIdx.x;
    if (d >= N_NODES) return;
    int pos = rowptr[d];
    csr_src[pos] = d;
    csr_ew[pos] = ewsum[0] * (1.0f / N_EDGES);
    csr_ew[(size_t)EE + pos] = ewsum[1] * (1.0f / N_EDGES);
    csr_ew[2 * (size_t)EE + pos] = ewsum[2] * (1.0f / N_EDGES);
}

// ---------------------------------------------------------------------------
// SGEMM C[M,N] = act(A[M,128] @ B[128,N] + bias), fp32 SIMT, 64x64 tile
// ---------------------------------------------------------------------------
template <bool RELU, bool OUT_BF16>
__global__ __launch_bounds__(256) void sgemm_kernel(
    const float* __restrict__ A, const float* __restrict__ B,
    const float* __restrict__ bias, void* __restrict__ C, int M, int N) {
    const int BM = 64, BN = 64, BK = 16;
    __shared__ float As[BK][BM];
    __shared__ float Bs[BK][BN];
    int tid = threadIdx.x;
    int tx = tid & 15, ty = tid >> 4;
    int m0 = blockIdx.y * BM, n0 = blockIdx.x * BN;
    float acc[4][4] = {};
    int arow = tid >> 2;
    int acol = (tid & 3) * 4;
    int brow = tid >> 4;
    int bcol = (tid & 15) * 4;
    for (int k0 = 0; k0 < 128; k0 += BK) {
        float4 av = make_float4(0.f, 0.f, 0.f, 0.f);
        if (m0 + arow < M)
            av = *(const float4*)(A + (size_t)(m0 + arow) * 128 + k0 + acol);
        As[acol + 0][arow] = av.x;
        As[acol + 1][arow] = av.y;
        As[acol + 2][arow] = av.z;
        As[acol + 3][arow] = av.w;
        float4 bv = *(const float4*)(B + (size_t)(k0 + brow) * N + n0 + bcol);
        Bs[brow][bcol + 0] = bv.x;
        Bs[brow][bcol + 1] = bv.y;
        Bs[brow][bcol + 2] = bv.z;
        Bs[brow][bcol + 3] = bv.w;
        __syncthreads();
#pragma unroll
        for (int kk = 0; kk < BK; kk++) {
            float a[4], b[4];
#pragma unroll
            for (int i = 0; i < 4; i++) a[i] = As[kk][ty * 4 + i];
#pragma unroll
            for (int j = 0; j < 4; j++) b[j] = Bs[kk][tx * 4 + j];
#pragma unroll
            for (int i = 0; i < 4; i++)
#pragma unroll
                for (int j = 0; j < 4; j++) acc[i][j] += a[i] * b[j];
        }
        __syncthreads();
    }
#pragma unroll
    for (int i = 0; i < 4; i++) {
        int row = m0 + ty * 4 + i;
        if (row >= M) continue;
#pragma unroll
        for (int j = 0; j < 4; j++) {
            int col = n0 + tx * 4 + j;
            float v = acc[i][j];
            if (bias) v += bias[col];
            if (RELU) v = v > 0.f ? v : 0.f;
            if (OUT_BF16)
                ((bfraw*)C)[(size_t)row * N + col] = f2b(v);
            else
                ((float*)C)[(size_t)row * N + col] = v;
        }
    }
}

// ---------------------------------------------------------------------------
// a_s[n,hd] = dot(h[n,hd,:], att_src[hd,:]); same for a_d
// ---------------------------------------------------------------------------
__global__ __launch_bounds__(256) void att_kernel(
    const bfraw* __restrict__ h, const float* __restrict__ att_s_l,
    const float* __restrict__ att_d_l, float* __restrict__ a_s, float* __restrict__ a_d) {
    __shared__ float ss[HEADS * HID], sd[HEADS * HID];
    int tid = threadIdx.x;
    for (int i = tid; i < HEADS * HID; i += 256) {
        ss[i] = att_s_l[i];
        sd[i] = att_d_l[i];
    }
    __syncthreads();
    long long gid = (long long)blockIdx.x * 256 + tid;
    if (gid >= (long long)N_NODES * HEADS) return;
    int n = (int)(gid >> 2), hd = (int)(gid & 3);
    const uint4* hv = (const uint4*)(h + (size_t)n * (HEADS * HID) + hd * HID);
    const float* ssp = ss + hd * HID;
    const float* sdp = sd + hd * HID;
    float s = 0.f, d = 0.f;
#pragma unroll
    for (int i = 0; i < 16; i++) {
        uint4 u = hv[i];
        unsigned w[4] = {u.x, u.y, u.z, u.w};
#pragma unroll
        for (int j = 0; j < 4; j++) {
            float lo = __uint_as_float(w[j] << 16);
            float hi = __uint_as_float(w[j] & 0xffff0000u);
            int c = i * 8 + j * 2;
            s += lo * ssp[c] + hi * ssp[c + 1];
            d += lo * sdp[c] + hi * sdp[c + 1];
        }
    }
    a_s[gid] = s;
    a_d[gid] = d;
}

// ---------------------------------------------------------------------------
// softmax over incoming edges (CSR): one thread per dst node, no atomics.
// writes unnormalized ex to alpha[], and invd[d] = 0.25/denom (head-mean folded)
// ---------------------------------------------------------------------------
__global__ __launch_bounds__(256) void softmax_kernel(
    const int* __restrict__ rowptr, const int* __restrict__ csr_src,
    const float* __restrict__ csr_ew_l, const float* __restrict__ a_s,
    const float* __restrict__ a_d, float4* __restrict__ alpha,
    float4* __restrict__ invd) {
    int d = blockIdx.x * 256 + threadIdx.x;
    if (d >= N_NODES) return;
    int rs = rowptr[d], re = rowptr[d + 1];
    float4 ad4 = *(const float4*)(a_d + (size_t)d * 4);
    float m0 = -1e30f, m1 = -1e30f, m2 = -1e30f, m3 = -1e30f;
    for (int i = rs; i < re; i++) {
        int s = csr_src[i];
        float w = csr_ew_l[i];
        float4 as4 = *(const float4*)(a_s + (size_t)s * 4);
        m0 = fmaxf(m0, lrelu(as4.x + ad4.x + w));
        m1 = fmaxf(m1, lrelu(as4.y + ad4.y + w));
        m2 = fmaxf(m2, lrelu(as4.z + ad4.z + w));
        m3 = fmaxf(m3, lrelu(as4.w + ad4.w + w));
    }
    float s0 = 0.f, s1 = 0.f, s2 = 0.f, s3 = 0.f;
    for (int i = rs; i < re; i++) {
        int s = csr_src[i];
        float w = csr_ew_l[i];
        float4 as4 = *(const float4*)(a_s + (size_t)s * 4);
        float e0 = __expf(lrelu(as4.x + ad4.x + w) - m0);
        float e1 = __expf(lrelu(as4.y + ad4.y + w) - m1);
        float e2 = __expf(lrelu(as4.z + ad4.z + w) - m2);
        float e3 = __expf(lrelu(as4.w + ad4.w + w) - m3);
        s0 += e0; s1 += e1; s2 += e2; s3 += e3;
        alpha[i] = make_float4(e0, e1, e2, e3);
    }
    invd[d] = make_float4(0.25f / s0, 0.25f / s1, 0.25f / s2, 0.25f / s3);
}

// ---------------------------------------------------------------------------
// aggregate + bias + LayerNorm + residual + relu, fused. one wave per node.
// lane owns channels 2L, 2L+1. zero atomics; x updated in place.
// ---------------------------------------------------------------------------
__global__ __launch_bounds__(256) void agg_ln_kernel(
    const int* __restrict__ rowptr, const int* __restrict__ csr_src,
    const float4* __restrict__ alpha, const float4* __restrict__ invd,
    const bfraw* __restrict__ h, const float* __restrict__ bg,
    const float* __restrict__ gamma, const float* __restrict__ beta,
    float* __restrict__ x) {
    int node = blockIdx.x * 4 + (threadIdx.x >> 6);
    int lane = threadIdx.x & 63;
    if (node >= N_NODES) return;
    int rs = rowptr[node], re = rowptr[node + 1];
    float a00 = 0.f, a01 = 0.f, a10 = 0.f, a11 = 0.f;
    float a20 = 0.f, a21 = 0.f, a30 = 0.f, a31 = 0.f;
    for (int i = rs; i < re; i++) {
        float4 al = alpha[i];
        int s = csr_src[i];
        const bfraw* hr = h + (size_t)s * (HEADS * HID) + 2 * lane;
        ushort2 u0 = *(const ushort2*)(hr);
        ushort2 u1 = *(const ushort2*)(hr + 128);
        ushort2 u2 = *(const ushort2*)(hr + 256);
        ushort2 u3 = *(const ushort2*)(hr + 384);
        a00 += al.x * b2f(u0.x); a01 += al.x * b2f(u0.y);
        a10 += al.y * b2f(u1.x); a11 += al.y * b2f(u1.y);
        a20 += al.z * b2f(u2.x); a21 += al.z * b2f(u2.y);
        a30 += al.w * b2f(u3.x); a31 += al.w * b2f(u3.y);
    }
    float4 iv = invd[node];
    int c0 = 2 * lane, c1 = 2 * lane + 1;
    float y0 = a00 * iv.x + a10 * iv.y + a20 * iv.z + a30 * iv.w + bg[c0];
    float y1 = a01 * iv.x + a11 * iv.y + a21 * iv.z + a31 * iv.w + bg[c1];
    float sum = y0 + y1;
    for (int o = 32; o; o >>= 1) sum += __shfl_xor(sum, o);
    float mu = sum * (1.f / HID);
    float d0 = y0 - mu, d1 = y1 - mu;
    float vs = d0 * d0 + d1 * d1;
    for (int o = 32; o; o >>= 1) vs += __shfl_xor(vs, o);
    float r = rsqrtf(vs * (1.f / HID) + LN_EPS);
    float o0 = d0 * r * gamma[c0] + beta[c0];
    float o1 = d1 * r * gamma[c1] + beta[c1];
    float2* xp = (float2*)(x + (size_t)node * HID) + lane;
    float2 xv = *xp;
    xv.x = fmaxf(xv.x + o0, 0.f);
    xv.y = fmaxf(xv.y + o1, 0.f);
    *xp = xv;
}

extern "C" void kernel_launch(void* const* d_in, const int* in_sizes, int n_in,
                              void* d_out, int out_size, void* d_ws, size_t ws_size,
                              hipStream_t stream) {
    const float* nf      = (const float*)d_in[0];
    const int*   ei      = (const int*)d_in[1];
    const float* ea      = (const float*)d_in[2];
    const float* W0      = (const float*)d_in[3];
    const float* b0      = (const float*)d_in[4];
    const float* We      = (const float*)d_in[5];
    const float* be      = (const float*)d_in[6];
    const float* Wg      = (const float*)d_in[7];
    const float* att_src = (const float*)d_in[8];
    const float* att_dst = (const float*)d_in[9];
    const float* bg      = (const float*)d_in[10];
    const float* gamma   = (const float*)d_in[11];
    const float* beta    = (const float*)d_in[12];
    float* x = (float*)d_out;  // x lives in d_out throughout

    char* p = (char*)d_ws;
    auto alloc = [&](size_t bytes) -> void* {
        void* r = (void*)p;
        p += (bytes + 255) & ~(size_t)255;
        return r;
    };
    bfraw*  h       = (bfraw*)alloc((size_t)N_NODES * HEADS * HID * sizeof(bfraw));
    float4* alpha   = (float4*)alloc((size_t)EE * sizeof(float4));
    float*  a_s     = (float*)alloc((size_t)N_NODES * HEADS * sizeof(float));
    float*  a_d     = (float*)alloc((size_t)N_NODES * HEADS * sizeof(float));
    float*  ew      = (float*)alloc((size_t)N_LAYERS * N_EDGES * sizeof(float));
    int*    csr_src = (int*)alloc((size_t)EE * sizeof(int));
    float*  csr_ew  = (float*)alloc((size_t)N_LAYERS * EE * sizeof(float));
    int*    rowptr  = (int*)alloc((size_t)(N_NODES + 1) * sizeof(int));
    int*    deg     = (int*)alloc((size_t)N_NODES * sizeof(int));
    int*    woff    = (int*)alloc((size_t)N_NODES * sizeof(int));
    float4* invd    = (float4*)alloc((size_t)N_NODES * sizeof(float4));
    float*  wem     = (float*)alloc((size_t)N_LAYERS * D_EDGE * sizeof(float));
    float*  bem     = (float*)alloc((size_t)N_LAYERS * sizeof(float));
    float*  ewsum   = (float*)alloc((size_t)N_LAYERS * sizeof(float));
    float*  partial = (float*)alloc((size_t)N_LAYERS * EW_GRID * sizeof(float));
    size_t need = (size_t)(p - (char*)d_ws);
    if (need > ws_size) {
        fprintf(stderr, "kernel_launch: workspace too small: need %zu have %zu\n", need, ws_size);
        return;
    }

    prep_kernel<<<1, 256, 0, stream>>>(We, be, wem, bem);
    ew_kernel<<<EW_GRID, 256, 0, stream>>>(ea, wem, bem, ew, partial);
    ewred_kernel<<<N_LAYERS, 256, 0, stream>>>(partial, bem, ewsum);

    // CSR build (per call — inputs re-poisoned every replay)
    deginit_kernel<<<(N_NODES + 255) / 256, 256, 0, stream>>>(deg);
    hist_kernel<<<(N_EDGES + 255) / 256, 256, 0, stream>>>(ei, deg);
    scan_kernel<<<1, SCAN_THREADS, 0, stream>>>(deg, rowptr, woff);
    scatter_kernel<<<(N_EDGES + 255) / 256, 256, 0, stream>>>(ei, ew, woff, csr_src, csr_ew);
    selfloop_kernel<<<(N_NODES + 255) / 256, 256, 0, stream>>>(rowptr, ewsum, csr_src, csr_ew);

    // node encoder: x = relu(nf @ W0 + b0)
    sgemm_kernel<true, false><<<dim3(HID / 64, (N_NODES + 63) / 64), 256, 0, stream>>>(
        nf, W0, b0, (void*)x, N_NODES, HID);

    for (int l = 0; l < N_LAYERS; l++) {
        sgemm_kernel<false, true><<<dim3(HEADS * HID / 64, (N_NODES + 63) / 64), 256, 0, stream>>>(
            x, Wg + (size_t)l * HID * HEADS * HID, nullptr, (void*)h, N_NODES, HEADS * HID);
        att_kernel<<<((long long)N_NODES * HEADS + 255) / 256, 256, 0, stream>>>(
            h, att_src + (size_t)l * HEADS * HID, att_dst + (size_t)l * HEADS * HID, a_s, a_d);
        softmax_kernel<<<(N_NODES + 255) / 256, 256, 0, stream>>>(
            rowptr, csr_src, csr_ew + (size_t)l * EE, a_s, a_d, alpha, invd);
        agg_ln_kernel<<<(N_NODES + 3) / 4, 256, 0, stream>>>(
            rowptr, csr_src, alpha, invd, h, bg + (size_t)l * HID,
            gamma + (size_t)l * HID, beta + (size_t)l * HID, x);
    }
}

// Round 4
// 2285.256 us; speedup vs baseline: 2.7147x; 1.1637x over previous
//
#include <hip/hip_runtime.h>
#include <hip/hip_bf16.h>
#include <cstdio>

#define N_NODES 100000
#define N_EDGES 1600000
#define D_NODE 128
#define D_EDGE 64
#define HID 128
#define HEADS 4
#define N_LAYERS 3
#define LN_EPS 1e-5f
#define NEG_SLOPE 0.2f
#define EE (N_EDGES + N_NODES)            // edges incl. self-loops
#define EW_GRID ((N_EDGES + 255) / 256)   // 6250 blocks
#define SCAN_THREADS 1024
#define SCAN_CHUNK ((N_NODES + SCAN_THREADS - 1) / SCAN_THREADS)  // 98

typedef unsigned short bfraw;
using bf16x8 = __attribute__((ext_vector_type(8))) short;
using f32x4  = __attribute__((ext_vector_type(4))) float;

__device__ __forceinline__ float b2f(bfraw u) {
    return __uint_as_float(((unsigned)u) << 16);
}
__device__ __forceinline__ bfraw f2b(float f) {
    unsigned u = __float_as_uint(f);
    unsigned r = (u + 0x7fffu + ((u >> 16) & 1u)) >> 16;
    return (bfraw)r;
}
__device__ __forceinline__ float lrelu(float v) {
    return v > 0.f ? v : NEG_SLOPE * v;
}

// ---------------------------------------------------------------------------
// prep: wem[l][d] = mean_j We[l][d][j]; bem[l] = mean(be[l])
// ---------------------------------------------------------------------------
__global__ __launch_bounds__(256) void prep_kernel(
    const float* __restrict__ We, const float* __restrict__ be,
    float* __restrict__ wem, float* __restrict__ bem) {
    int tid = threadIdx.x;
    if (tid < N_LAYERS * D_EDGE) {
        int l = tid / D_EDGE, d = tid % D_EDGE;
        const float* row = We + ((size_t)l * D_EDGE + d) * HID;
        float s = 0.f;
        for (int j = 0; j < HID; j++) s += row[j];
        wem[tid] = s * (1.0f / HID);
    } else if (tid < N_LAYERS * D_EDGE + N_LAYERS) {
        int l = tid - N_LAYERS * D_EDGE;
        const float* row = be + (size_t)l * HID;
        float s = 0.f;
        for (int j = 0; j < HID; j++) s += row[j];
        bem[l] = s * (1.0f / HID);
    }
}

// ---------------------------------------------------------------------------
// ew[l][e] = dot(edge_attr[e], wem[l]) + bem[l]; block partials (no atomics)
// ---------------------------------------------------------------------------
__global__ __launch_bounds__(256) void ew_kernel(
    const float* __restrict__ ea, const float* __restrict__ wem,
    const float* __restrict__ bem, float* __restrict__ ew,
    float* __restrict__ partial) {
    __shared__ float wsh[N_LAYERS * D_EDGE];
    __shared__ float bsh[N_LAYERS];
    __shared__ float red[4][3];
    int tid = threadIdx.x;
    if (tid < N_LAYERS * D_EDGE) wsh[tid] = wem[tid];
    if (tid < N_LAYERS) bsh[tid] = bem[tid];
    __syncthreads();
    long long e = (long long)blockIdx.x * 256 + tid;
    float d0 = 0.f, d1 = 0.f, d2 = 0.f;
    if (e < N_EDGES) {
        const float4* row = (const float4*)(ea + (size_t)e * D_EDGE);
#pragma unroll
        for (int i = 0; i < D_EDGE / 4; i++) {
            float4 v = row[i];
            int c = i * 4;
            d0 += v.x * wsh[c] + v.y * wsh[c + 1] + v.z * wsh[c + 2] + v.w * wsh[c + 3];
            d1 += v.x * wsh[64 + c] + v.y * wsh[64 + c + 1] + v.z * wsh[64 + c + 2] + v.w * wsh[64 + c + 3];
            d2 += v.x * wsh[128 + c] + v.y * wsh[128 + c + 1] + v.z * wsh[128 + c + 2] + v.w * wsh[128 + c + 3];
        }
        ew[e] = d0 + bsh[0];
        ew[(size_t)N_EDGES + e] = d1 + bsh[1];
        ew[2 * (size_t)N_EDGES + e] = d2 + bsh[2];
    }
    float s0 = d0, s1 = d1, s2 = d2;
    for (int o = 32; o; o >>= 1) {
        s0 += __shfl_xor(s0, o);
        s1 += __shfl_xor(s1, o);
        s2 += __shfl_xor(s2, o);
    }
    int wid = tid >> 6;
    if ((tid & 63) == 0) {
        red[wid][0] = s0;
        red[wid][1] = s1;
        red[wid][2] = s2;
    }
    __syncthreads();
    if (tid < 3) {
        partial[(size_t)tid * EW_GRID + blockIdx.x] =
            red[0][tid] + red[1][tid] + red[2][tid] + red[3][tid];
    }
}

__global__ __launch_bounds__(256) void ewred_kernel(
    const float* __restrict__ partial, const float* __restrict__ bem,
    float* __restrict__ ewsum) {
    __shared__ float red[4];
    int l = blockIdx.x;
    int tid = threadIdx.x;
    float s = 0.f;
    for (int i = tid; i < EW_GRID; i += 256) s += partial[(size_t)l * EW_GRID + i];
    for (int o = 32; o; o >>= 1) s += __shfl_xor(s, o);
    int wid = tid >> 6;
    if ((tid & 63) == 0) red[wid] = s;
    __syncthreads();
    if (tid == 0)
        ewsum[l] = red[0] + red[1] + red[2] + red[3] + bem[l] * (float)N_EDGES;
}

// ---------------------------------------------------------------------------
// CSR build: deg=1 (self-loop) -> histogram -> single-block scan -> scatter
// ---------------------------------------------------------------------------
__global__ __launch_bounds__(256) void deginit_kernel(int* __restrict__ deg) {
    int i = blockIdx.x * 256 + threadIdx.x;
    if (i < N_NODES) deg[i] = 1;
}

__global__ __launch_bounds__(256) void hist_kernel(
    const int* __restrict__ ei, int* __restrict__ deg) {
    int e = blockIdx.x * 256 + threadIdx.x;
    if (e < N_EDGES) atomicAdd(&deg[ei[N_EDGES + e]], 1);
}

__global__ __launch_bounds__(SCAN_THREADS) void scan_kernel(
    const int* __restrict__ deg, int* __restrict__ rowptr, int* __restrict__ woff) {
    __shared__ int part[SCAN_THREADS];
    int tid = threadIdx.x;
    int lo = tid * SCAN_CHUNK;
    int hi = lo + SCAN_CHUNK < N_NODES ? lo + SCAN_CHUNK : N_NODES;
    int s = 0;
    for (int i = lo; i < hi; i++) s += deg[i];
    part[tid] = s;
    __syncthreads();
    for (int off = 1; off < SCAN_THREADS; off <<= 1) {
        int t = (tid >= off) ? part[tid - off] : 0;
        __syncthreads();
        part[tid] += t;
        __syncthreads();
    }
    int run = (tid == 0) ? 0 : part[tid - 1];
    for (int i = lo; i < hi; i++) {
        rowptr[i] = run;
        woff[i] = run + 1;  // slot 0 reserved for self-loop
        run += deg[i];
    }
    if (tid == 0) rowptr[N_NODES] = EE;
}

__global__ __launch_bounds__(256) void scatter_kernel(
    const int* __restrict__ ei, const float* __restrict__ ew,
    int* __restrict__ woff, int* __restrict__ csr_src,
    float* __restrict__ csr_ew) {
    int e = blockIdx.x * 256 + threadIdx.x;
    if (e >= N_EDGES) return;
    int d = ei[N_EDGES + e];
    int pos = atomicAdd(&woff[d], 1);
    csr_src[pos] = ei[e];
    csr_ew[pos] = ew[e];
    csr_ew[(size_t)EE + pos] = ew[(size_t)N_EDGES + e];
    csr_ew[2 * (size_t)EE + pos] = ew[2 * (size_t)N_EDGES + e];
}

__global__ __launch_bounds__(256) void selfloop_kernel(
    const int* __restrict__ rowptr, const float* __restrict__ ewsum,
    int* __restrict__ csr_src, float* __restrict__ csr_ew) {
    int d = blockIdx.x * 256 + threadIdx.x;
    if (d >= N_NODES) return;
    int pos = rowptr[d];
    csr_src[pos] = d;
    csr_ew[pos] = ewsum[0] * (1.0f / N_EDGES);
    csr_ew[(size_t)EE + pos] = ewsum[1] * (1.0f / N_EDGES);
    csr_ew[2 * (size_t)EE + pos] = ewsum[2] * (1.0f / N_EDGES);
}

// ---------------------------------------------------------------------------
// cast fp32 -> bf16 (vectorized, 4 elems/thread)
// ---------------------------------------------------------------------------
__global__ __launch_bounds__(256) void castnf_kernel(
    const float* __restrict__ in, bfraw* __restrict__ out, int n4) {
    int i = blockIdx.x * 256 + threadIdx.x;
    if (i >= n4) return;
    float4 v = *(const float4*)(in + (size_t)i * 4);
    ushort4 u;
    u.x = f2b(v.x); u.y = f2b(v.y); u.z = f2b(v.z); u.w = f2b(v.w);
    *(ushort4*)(out + (size_t)i * 4) = u;
}

// ---------------------------------------------------------------------------
// transpose+cast weights: in [L][128][N] fp32 -> out [L][N][128] bf16
// k = t&127 (contiguous writes), n = (t>>7)&(N-1), l = t>>(7+lgN)
// ---------------------------------------------------------------------------
__global__ __launch_bounds__(256) void tcast_kernel(
    const float* __restrict__ in, bfraw* __restrict__ out, int lgN, int total) {
    int t = blockIdx.x * 256 + threadIdx.x;
    if (t >= total) return;
    int k = t & 127;
    int n = (t >> 7) & ((1 << lgN) - 1);
    int l = t >> (7 + lgN);
    out[t] = f2b(in[((size_t)l << (7 + lgN)) + ((size_t)k << lgN) + n]);
}

// ---------------------------------------------------------------------------
// MFMA bf16 GEMM: C[M,N] = A[M,128] @ B[128,N], Bt pre-transposed [N][128].
// 64x64 tile, 4 waves; wave w owns 16-col strip. mfma_f32_16x16x32_bf16,
// layouts per m89/m91: A[m=lane&15][k=quad*8+j]; D col=lane&15, row=quad*4+r.
// EPI 0: store bf16 h. EPI 1: +bias, relu, store fp32 x AND bf16 xb.
// ---------------------------------------------------------------------------
template <int EPI>
__global__ __launch_bounds__(256) void gemm_mfma_kernel(
    const bfraw* __restrict__ A, const bfraw* __restrict__ Bt,
    const float* __restrict__ bias, bfraw* __restrict__ outb,
    float* __restrict__ outf, int M, int N) {
    __shared__ short Alds[64 * 136];  // +8 bf16 pad: 16B-aligned rows, bank spread
    __shared__ short Blds[64 * 136];
    int tid = threadIdx.x;
    int m0 = blockIdx.y * 64;
    int n0 = blockIdx.x * 64;
    {
        int li = tid;
#pragma unroll
        for (int i = 0; i < 4; i++, li += 256) {
            int row = li >> 4, ch = li & 15;
            uint4 v = make_uint4(0u, 0u, 0u, 0u);
            if (m0 + row < M)
                v = *(const uint4*)(A + (size_t)(m0 + row) * 128 + ch * 8);
            *(uint4*)&Alds[row * 136 + ch * 8] = v;
            uint4 bv = *(const uint4*)(Bt + (size_t)(n0 + row) * 128 + ch * 8);
            *(uint4*)&Blds[row * 136 + ch * 8] = bv;
        }
    }
    __syncthreads();
    int w = tid >> 6, lane = tid & 63;
    int quad = lane >> 4, lr = lane & 15;
    bf16x8 bfr[4];
#pragma unroll
    for (int kc = 0; kc < 4; kc++)
        bfr[kc] = *(const bf16x8*)&Blds[(w * 16 + lr) * 136 + kc * 32 + quad * 8];
#pragma unroll
    for (int mt = 0; mt < 4; mt++) {
        f32x4 acc = {0.f, 0.f, 0.f, 0.f};
#pragma unroll
        for (int kc = 0; kc < 4; kc++) {
            bf16x8 afr = *(const bf16x8*)&Alds[(mt * 16 + lr) * 136 + kc * 32 + quad * 8];
            acc = __builtin_amdgcn_mfma_f32_16x16x32_bf16(afr, bfr[kc], acc, 0, 0, 0);
        }
        int col = n0 + w * 16 + lr;
#pragma unroll
        for (int r = 0; r < 4; r++) {
            int row = m0 + mt * 16 + quad * 4 + r;
            if (row >= M) continue;
            float v = acc[r];
            if (EPI == 1) {
                v += bias[col];
                v = fmaxf(v, 0.f);
                outf[(size_t)row * 128 + col] = v;
                outb[(size_t)row * 128 + col] = f2b(v);
            } else {
                outb[(size_t)row * N + col] = f2b(v);
            }
        }
    }
}

// ---------------------------------------------------------------------------
// a_s[n,hd] = dot(h[n,hd,:], att_src[hd,:]); same for a_d
// ---------------------------------------------------------------------------
__global__ __launch_bounds__(256) void att_kernel(
    const bfraw* __restrict__ h, const float* __restrict__ att_s_l,
    const float* __restrict__ att_d_l, float* __restrict__ a_s, float* __restrict__ a_d) {
    __shared__ float ss[HEADS * HID], sd[HEADS * HID];
    int tid = threadIdx.x;
    for (int i = tid; i < HEADS * HID; i += 256) {
        ss[i] = att_s_l[i];
        sd[i] = att_d_l[i];
    }
    __syncthreads();
    long long gid = (long long)blockIdx.x * 256 + tid;
    if (gid >= (long long)N_NODES * HEADS) return;
    int n = (int)(gid >> 2), hd = (int)(gid & 3);
    const uint4* hv = (const uint4*)(h + (size_t)n * (HEADS * HID) + hd * HID);
    const float* ssp = ss + hd * HID;
    const float* sdp = sd + hd * HID;
    float s = 0.f, d = 0.f;
#pragma unroll
    for (int i = 0; i < 16; i++) {
        uint4 u = hv[i];
        unsigned wv[4] = {u.x, u.y, u.z, u.w};
#pragma unroll
        for (int j = 0; j < 4; j++) {
            float lo = __uint_as_float(wv[j] << 16);
            float hi = __uint_as_float(wv[j] & 0xffff0000u);
            int c = i * 8 + j * 2;
            s += lo * ssp[c] + hi * ssp[c + 1];
            d += lo * sdp[c] + hi * sdp[c + 1];
        }
    }
    a_s[gid] = s;
    a_d[gid] = d;
}

// ---------------------------------------------------------------------------
// softmax over incoming edges (CSR): one thread per dst node, no atomics.
// ---------------------------------------------------------------------------
__global__ __launch_bounds__(256) void softmax_kernel(
    const int* __restrict__ rowptr, const int* __restrict__ csr_src,
    const float* __restrict__ csr_ew_l, const float* __restrict__ a_s,
    const float* __restrict__ a_d, float4* __restrict__ alpha,
    float4* __restrict__ invd) {
    int d = blockIdx.x * 256 + threadIdx.x;
    if (d >= N_NODES) return;
    int rs = rowptr[d], re = rowptr[d + 1];
    float4 ad4 = *(const float4*)(a_d + (size_t)d * 4);
    float m0 = -1e30f, m1 = -1e30f, m2 = -1e30f, m3 = -1e30f;
    for (int i = rs; i < re; i++) {
        int s = csr_src[i];
        float w = csr_ew_l[i];
        float4 as4 = *(const float4*)(a_s + (size_t)s * 4);
        m0 = fmaxf(m0, lrelu(as4.x + ad4.x + w));
        m1 = fmaxf(m1, lrelu(as4.y + ad4.y + w));
        m2 = fmaxf(m2, lrelu(as4.z + ad4.z + w));
        m3 = fmaxf(m3, lrelu(as4.w + ad4.w + w));
    }
    float s0 = 0.f, s1 = 0.f, s2 = 0.f, s3 = 0.f;
    for (int i = rs; i < re; i++) {
        int s = csr_src[i];
        float w = csr_ew_l[i];
        float4 as4 = *(const float4*)(a_s + (size_t)s * 4);
        float e0 = __expf(lrelu(as4.x + ad4.x + w) - m0);
        float e1 = __expf(lrelu(as4.y + ad4.y + w) - m1);
        float e2 = __expf(lrelu(as4.z + ad4.z + w) - m2);
        float e3 = __expf(lrelu(as4.w + ad4.w + w) - m3);
        s0 += e0; s1 += e1; s2 += e2; s3 += e3;
        alpha[i] = make_float4(e0, e1, e2, e3);
    }
    invd[d] = make_float4(0.25f / s0, 0.25f / s1, 0.25f / s2, 0.25f / s3);
}

// ---------------------------------------------------------------------------
// aggregate + bias + LayerNorm + residual + relu, fused. one wave per node.
// also maintains bf16 shadow xb for the next layer's MFMA GEMM.
// ---------------------------------------------------------------------------
__global__ __launch_bounds__(256) void agg_ln_kernel(
    const int* __restrict__ rowptr, const int* __restrict__ csr_src,
    const float4* __restrict__ alpha, const float4* __restrict__ invd,
    const bfraw* __restrict__ h, const float* __restrict__ bg,
    const float* __restrict__ gamma, const float* __restrict__ beta,
    float* __restrict__ x, bfraw* __restrict__ xb) {
    int node = blockIdx.x * 4 + (threadIdx.x >> 6);
    int lane = threadIdx.x & 63;
    if (node >= N_NODES) return;
    int rs = rowptr[node], re = rowptr[node + 1];
    float a00 = 0.f, a01 = 0.f, a10 = 0.f, a11 = 0.f;
    float a20 = 0.f, a21 = 0.f, a30 = 0.f, a31 = 0.f;
    for (int i = rs; i < re; i++) {
        float4 al = alpha[i];
        int s = csr_src[i];
        const bfraw* hr = h + (size_t)s * (HEADS * HID) + 2 * lane;
        ushort2 u0 = *(const ushort2*)(hr);
        ushort2 u1 = *(const ushort2*)(hr + 128);
        ushort2 u2 = *(const ushort2*)(hr + 256);
        ushort2 u3 = *(const ushort2*)(hr + 384);
        a00 += al.x * b2f(u0.x); a01 += al.x * b2f(u0.y);
        a10 += al.y * b2f(u1.x); a11 += al.y * b2f(u1.y);
        a20 += al.z * b2f(u2.x); a21 += al.z * b2f(u2.y);
        a30 += al.w * b2f(u3.x); a31 += al.w * b2f(u3.y);
    }
    float4 iv = invd[node];
    int c0 = 2 * lane, c1 = 2 * lane + 1;
    float y0 = a00 * iv.x + a10 * iv.y + a20 * iv.z + a30 * iv.w + bg[c0];
    float y1 = a01 * iv.x + a11 * iv.y + a21 * iv.z + a31 * iv.w + bg[c1];
    float sum = y0 + y1;
    for (int o = 32; o; o >>= 1) sum += __shfl_xor(sum, o);
    float mu = sum * (1.f / HID);
    float d0 = y0 - mu, d1 = y1 - mu;
    float vs = d0 * d0 + d1 * d1;
    for (int o = 32; o; o >>= 1) vs += __shfl_xor(vs, o);
    float r = rsqrtf(vs * (1.f / HID) + LN_EPS);
    float o0 = d0 * r * gamma[c0] + beta[c0];
    float o1 = d1 * r * gamma[c1] + beta[c1];
    float2* xp = (float2*)(x + (size_t)node * HID) + lane;
    float2 xv = *xp;
    xv.x = fmaxf(xv.x + o0, 0.f);
    xv.y = fmaxf(xv.y + o1, 0.f);
    *xp = xv;
    ushort2 ub;
    ub.x = f2b(xv.x);
    ub.y = f2b(xv.y);
    *(ushort2*)(xb + (size_t)node * HID) + 0;  // no-op to keep addressing clear
    *(ushort2*)(xb + (size_t)node * HID + 2 * lane) = ub;
}

extern "C" void kernel_launch(void* const* d_in, const int* in_sizes, int n_in,
                              void* d_out, int out_size, void* d_ws, size_t ws_size,
                              hipStream_t stream) {
    const float* nf      = (const float*)d_in[0];
    const int*   ei      = (const int*)d_in[1];
    const float* ea      = (const float*)d_in[2];
    const float* W0      = (const float*)d_in[3];
    const float* b0      = (const float*)d_in[4];
    const float* We      = (const float*)d_in[5];
    const float* be      = (const float*)d_in[6];
    const float* Wg      = (const float*)d_in[7];
    const float* att_src = (const float*)d_in[8];
    const float* att_dst = (const float*)d_in[9];
    const float* bg      = (const float*)d_in[10];
    const float* gamma   = (const float*)d_in[11];
    const float* beta    = (const float*)d_in[12];
    float* x = (float*)d_out;  // x lives in d_out throughout

    char* p = (char*)d_ws;
    auto alloc = [&](size_t bytes) -> void* {
        void* r = (void*)p;
        p += (bytes + 255) & ~(size_t)255;
        return r;
    };
    bfraw*  h       = (bfraw*)alloc((size_t)N_NODES * HEADS * HID * sizeof(bfraw));
    float4* alpha   = (float4*)alloc((size_t)EE * sizeof(float4));
    bfraw*  xb      = (bfraw*)alloc((size_t)N_NODES * HID * sizeof(bfraw));
    float*  a_s     = (float*)alloc((size_t)N_NODES * HEADS * sizeof(float));
    float*  a_d     = (float*)alloc((size_t)N_NODES * HEADS * sizeof(float));
    float*  ew      = (float*)alloc((size_t)N_LAYERS * N_EDGES * sizeof(float));
    int*    csr_src = (int*)alloc((size_t)EE * sizeof(int));
    float*  csr_ew  = (float*)alloc((size_t)N_LAYERS * EE * sizeof(float));
    int*    rowptr  = (int*)alloc((size_t)(N_NODES + 1) * sizeof(int));
    int*    deg     = (int*)alloc((size_t)N_NODES * sizeof(int));
    int*    woff    = (int*)alloc((size_t)N_NODES * sizeof(int));
    float4* invd    = (float4*)alloc((size_t)N_NODES * sizeof(float4));
    float*  wem     = (float*)alloc((size_t)N_LAYERS * D_EDGE * sizeof(float));
    float*  bem     = (float*)alloc((size_t)N_LAYERS * sizeof(float));
    float*  ewsum   = (float*)alloc((size_t)N_LAYERS * sizeof(float));
    float*  partial = (float*)alloc((size_t)N_LAYERS * EW_GRID * sizeof(float));
    bfraw*  W0bt    = (bfraw*)alloc((size_t)HID * D_NODE * sizeof(bfraw));
    bfraw*  Wgbt    = (bfraw*)alloc((size_t)N_LAYERS * HEADS * HID * HID * sizeof(bfraw));
    size_t need = (size_t)(p - (char*)d_ws);
    if (need > ws_size) {
        fprintf(stderr, "kernel_launch: workspace too small: need %zu have %zu\n", need, ws_size);
        return;
    }
    // nfb (bf16 node_features) aliases alpha: alpha is first written in layer-0
    // softmax, long after the encoder GEMM consumed nfb. 27.2MB >= 25.6MB.
    bfraw* nfb = (bfraw*)alpha;

    prep_kernel<<<1, 256, 0, stream>>>(We, be, wem, bem);
    ew_kernel<<<EW_GRID, 256, 0, stream>>>(ea, wem, bem, ew, partial);
    ewred_kernel<<<N_LAYERS, 256, 0, stream>>>(partial, bem, ewsum);

    // CSR build
    deginit_kernel<<<(N_NODES + 255) / 256, 256, 0, stream>>>(deg);
    hist_kernel<<<(N_EDGES + 255) / 256, 256, 0, stream>>>(ei, deg);
    scan_kernel<<<1, SCAN_THREADS, 0, stream>>>(deg, rowptr, woff);
    scatter_kernel<<<(N_EDGES + 255) / 256, 256, 0, stream>>>(ei, ew, woff, csr_src, csr_ew);
    selfloop_kernel<<<(N_NODES + 255) / 256, 256, 0, stream>>>(rowptr, ewsum, csr_src, csr_ew);

    // bf16 conversions for MFMA
    castnf_kernel<<<((N_NODES * D_NODE / 4) + 255) / 256, 256, 0, stream>>>(
        nf, nfb, N_NODES * D_NODE / 4);
    tcast_kernel<<<(HID * D_NODE + 255) / 256, 256, 0, stream>>>(
        W0, W0bt, 7, HID * D_NODE);                       // [128][128] -> [128][128]^T
    tcast_kernel<<<(N_LAYERS * HID * HEADS * HID + 255) / 256, 256, 0, stream>>>(
        Wg, Wgbt, 9, N_LAYERS * HID * HEADS * HID);       // [3][128][512] -> [3][512][128]

    // node encoder: x = relu(nf @ W0 + b0), + bf16 shadow xb
    gemm_mfma_kernel<1><<<dim3(HID / 64, (N_NODES + 63) / 64), 256, 0, stream>>>(
        nfb, W0bt, b0, xb, x, N_NODES, HID);

    for (int l = 0; l < N_LAYERS; l++) {
        gemm_mfma_kernel<0><<<dim3(HEADS * HID / 64, (N_NODES + 63) / 64), 256, 0, stream>>>(
            xb, Wgbt + (size_t)l * HEADS * HID * HID, nullptr, h, nullptr,
            N_NODES, HEADS * HID);
        att_kernel<<<((long long)N_NODES * HEADS + 255) / 256, 256, 0, stream>>>(
            h, att_src + (size_t)l * HEADS * HID, att_dst + (size_t)l * HEADS * HID, a_s, a_d);
        softmax_kernel<<<(N_NODES + 255) / 256, 256, 0, stream>>>(
            rowptr, csr_src, csr_ew + (size_t)l * EE, a_s, a_d, alpha, invd);
        agg_ln_kernel<<<(N_NODES + 3) / 4, 256, 0, stream>>>(
            rowptr, csr_src, alpha, invd, h, bg + (size_t)l * HID,
            gamma + (size_t)l * HID, beta + (size_t)l * HID, x, xb);
    }
}